// Round 1
// baseline (1603.210 us; speedup 1.0000x reference)
//
#include <hip/hip_runtime.h>
#include <math.h>

#define HWPIX 16384

typedef unsigned short u16;
typedef __attribute__((ext_vector_type(8))) short short8;
typedef __attribute__((ext_vector_type(4))) float f32x4;

__device__ __forceinline__ float bf2f(u16 h) { return __uint_as_float(((unsigned)h) << 16); }
__device__ __forceinline__ u16 f2bf(float f) {
  unsigned u = __float_as_uint(f);
  u += 0x7fffu + ((u >> 16) & 1u);
  return (u16)(u >> 16);
}

#define MFMA16(a, b, c) __builtin_amdgcn_mfma_f32_16x16x32_bf16((a), (b), (c), 0, 0, 0)

// ---------------- K0: weight prep (bf16 transpose) + rel-pos bias table ----------------
__global__ __launch_bounds__(256) void k0_prep(
    const float* __restrict__ qkv_w, const float* __restrict__ proj_w,
    const float* __restrict__ fc1_w, const float* __restrict__ fc2_w,
    const float* __restrict__ relb,
    u16* __restrict__ wqkv, u16* __restrict__ wproj,
    u16* __restrict__ wfc1, u16* __restrict__ wfc2, float* __restrict__ bias12) {
  int e = blockIdx.x * 256 + threadIdx.x;
  if (e < 442368) { int o = e / 384, i = e % 384; wqkv[e] = f2bf(qkv_w[i * 1152 + o]); return; }
  e -= 442368;
  if (e < 147456) { int o = e / 384, i = e % 384; wproj[e] = f2bf(proj_w[i * 384 + o]); return; }
  e -= 147456;
  if (e < 294912) { int o = e / 384, i = e % 384; wfc1[e] = f2bf(fc1_w[i * 768 + o]); return; }
  e -= 294912;
  if (e < 294912) { int o = e / 768, i = e % 768; wfc2[e] = f2bf(fc2_w[i * 384 + o]); return; }
  e -= 294912;
  if (e < 49152) {
    int h = e / 4096, r = e % 4096, n = r / 64, m = r % 64;
    int dy = n / 8 - m / 8 + 7, dx = n % 8 - m % 8 + 7;
    bias12[e] = relb[(dy * 15 + dx) * 12 + h];
  }
}

// ---------------- K1: LayerNorm1 + NCHW->(token,C) transpose, bf16 out ----------------
__global__ __launch_bounds__(256) void k1_ln1(const float* __restrict__ x,
                                              const float* __restrict__ nw,
                                              const float* __restrict__ nb,
                                              u16* __restrict__ xn) {
  __shared__ alignas(16) u16 raw[64][392];
  __shared__ float psum[4][64], psq[4][64];
  int win = blockIdx.x;
  int b = win >> 8, s = win & 255;
  int wave = threadIdx.x >> 6, lane = threadIdx.x & 63;
  const float* xb = x + (size_t)b * 384 * HWPIX + s * 64 + lane;
  float sum = 0.f, sq = 0.f;
  for (int c = wave; c < 384; c += 4) {
    float v = xb[(size_t)c * HWPIX];
    sum += v; sq += v * v;
    raw[lane][c] = f2bf(v);
  }
  psum[wave][lane] = sum; psq[wave][lane] = sq;
  __syncthreads();
#pragma unroll
  for (int tt = 0; tt < 2; tt++) {
    int t = tt * 32 + wave * 8 + (lane >> 3);
    float s4 = psum[0][t] + psum[1][t] + psum[2][t] + psum[3][t];
    float q4 = psq[0][t] + psq[1][t] + psq[2][t] + psq[3][t];
    float m = s4 * (1.0f / 384.0f);
    float rstd = rsqrtf(q4 * (1.0f / 384.0f) - m * m + 1e-5f);
    u16* orow = xn + ((size_t)win * 64 + t) * 384;
#pragma unroll
    for (int it = 0; it < 12; it++) {
      int c = (lane & 7) * 4 + it * 32;
      ushort4 rv = *(const ushort4*)&raw[t][c];
      float4 nwv = *(const float4*)&nw[c];
      float4 nbv = *(const float4*)&nb[c];
      ushort4 ov;
      ov.x = f2bf((bf2f(rv.x) - m) * rstd * nwv.x + nbv.x);
      ov.y = f2bf((bf2f(rv.y) - m) * rstd * nwv.y + nbv.y);
      ov.z = f2bf((bf2f(rv.z) - m) * rstd * nwv.z + nbv.z);
      ov.w = f2bf((bf2f(rv.w) - m) * rstd * nwv.w + nbv.w);
      *(ushort4*)&orow[c] = ov;
    }
  }
}

// ---------------- shared 128x128 tile MFMA step ----------------
__device__ __forceinline__ void tile_step_128(const u16* As, const u16* Bs, int wr, int wc,
                                              int l15, int quad, f32x4 acc[4][4]) {
  short8 af[4], bf[4];
#pragma unroll
  for (int i = 0; i < 4; i++)
    af[i] = *(const short8*)&As[(wr * 64 + i * 16 + l15) * 32 + quad * 8];
#pragma unroll
  for (int j = 0; j < 4; j++)
    bf[j] = *(const short8*)&Bs[(wc * 64 + j * 16 + l15) * 32 + quad * 8];
#pragma unroll
  for (int i = 0; i < 4; i++)
#pragma unroll
    for (int j = 0; j < 4; j++)
      acc[i][j] = MFMA16(af[i], bf[j], acc[i][j]);
}

// ---------------- K2: QKV GEMM + scatter to q/k/vT layouts ----------------
__global__ __launch_bounds__(256) void k2_qkv(const u16* __restrict__ xn, const u16* __restrict__ wt,
                                              const float* __restrict__ bias,
                                              u16* __restrict__ qb, u16* __restrict__ kb,
                                              u16* __restrict__ vtb) {
  __shared__ alignas(16) u16 As[128 * 32];
  __shared__ alignas(16) u16 Bs[128 * 32];
  int tid = threadIdx.x, lane = tid & 63, wave = tid >> 6;
  int l15 = lane & 15, quad = lane >> 4;
  int wr = wave >> 1, wc = wave & 1;
  int mblk = blockIdx.x % 1024, nblk = blockIdx.x / 1024;
  int row0 = mblk * 128, col0 = nblk * 128;
  f32x4 z = {0.f, 0.f, 0.f, 0.f};
  f32x4 acc[4][4];
#pragma unroll
  for (int i = 0; i < 4; i++)
#pragma unroll
    for (int j = 0; j < 4; j++) acc[i][j] = z;
  int sr = tid >> 2, sc = (tid & 3) * 8;
  for (int k0 = 0; k0 < 384; k0 += 32) {
    __syncthreads();
    *(short8*)&As[sr * 32 + sc] = *(const short8*)&xn[(size_t)(row0 + sr) * 384 + k0 + sc];
    *(short8*)&As[(sr + 64) * 32 + sc] = *(const short8*)&xn[(size_t)(row0 + sr + 64) * 384 + k0 + sc];
    *(short8*)&Bs[sr * 32 + sc] = *(const short8*)&wt[(size_t)(col0 + sr) * 384 + k0 + sc];
    *(short8*)&Bs[(sr + 64) * 32 + sc] = *(const short8*)&wt[(size_t)(col0 + sr + 64) * 384 + k0 + sc];
    __syncthreads();
    tile_step_128(As, Bs, wr, wc, l15, quad, acc);
  }
#pragma unroll
  for (int j = 0; j < 4; j++) {
    int ocol = col0 + wc * 64 + j * 16 + l15;
    float bo = bias[ocol];
    int part = ocol / 384, within = ocol % 384;
    int h = within / 32, d = within % 32;
#pragma unroll
    for (int i = 0; i < 4; i++) {
#pragma unroll
      for (int r = 0; r < 4; r++) {
        int row = row0 + wr * 64 + i * 16 + quad * 4 + r;
        int win = row >> 6, tok = row & 63;
        float val = acc[i][j][r] + bo;
        if (part == 0)
          qb[(size_t)((win * 12 + h) * 64 + tok) * 32 + d] = f2bf(val * 0.17677669529663687f);
        else if (part == 1)
          kb[(size_t)((win * 12 + h) * 64 + tok) * 32 + d] = f2bf(val);
        else
          vtb[(size_t)((win * 12 + h) * 32 + d) * 64 + tok] = f2bf(val);
      }
    }
  }
}

// ---------------- K3: windowed attention (one wave per (window,head)) ----------------
__global__ __launch_bounds__(256) void k3_attn(const u16* __restrict__ qb, const u16* __restrict__ kb,
                                               const u16* __restrict__ vtb,
                                               const float* __restrict__ bias12,
                                               u16* __restrict__ ao) {
  __shared__ alignas(16) u16 P[4][64 * 72];
  int tid = threadIdx.x, lane = tid & 63, wave = tid >> 6;
  int l15 = lane & 15, quad = lane >> 4;
  int wh = blockIdx.x * 4 + wave;
  int win = wh / 12, h = wh % 12;
  const u16* qh = qb + (size_t)wh * 2048;
  const u16* kh = kb + (size_t)wh * 2048;
  const u16* vh = vtb + (size_t)wh * 2048;
  short8 aq[4], bk[4];
#pragma unroll
  for (int t = 0; t < 4; t++) {
    aq[t] = *(const short8*)&qh[(t * 16 + l15) * 32 + quad * 8];
    bk[t] = *(const short8*)&kh[(t * 16 + l15) * 32 + quad * 8];
  }
  f32x4 z = {0.f, 0.f, 0.f, 0.f};
  f32x4 S[4][4];
#pragma unroll
  for (int mt = 0; mt < 4; mt++)
#pragma unroll
    for (int nt = 0; nt < 4; nt++) S[mt][nt] = MFMA16(aq[mt], bk[nt], z);
  const float* bh = bias12 + h * 4096;
#pragma unroll
  for (int mt = 0; mt < 4; mt++)
#pragma unroll
    for (int rr = 0; rr < 4; rr++) {
      int rown = mt * 16 + quad * 4 + rr;
#pragma unroll
      for (int nt = 0; nt < 4; nt++) S[mt][nt][rr] += bh[rown * 64 + nt * 16 + l15];
    }
#pragma unroll
  for (int mt = 0; mt < 4; mt++)
#pragma unroll
    for (int rr = 0; rr < 4; rr++) {
      float mx = S[mt][0][rr];
      mx = fmaxf(mx, S[mt][1][rr]);
      mx = fmaxf(mx, S[mt][2][rr]);
      mx = fmaxf(mx, S[mt][3][rr]);
#pragma unroll
      for (int m = 1; m < 16; m <<= 1) mx = fmaxf(mx, __shfl_xor(mx, m, 64));
      float pv[4], se = 0.f;
#pragma unroll
      for (int nt = 0; nt < 4; nt++) { pv[nt] = __expf(S[mt][nt][rr] - mx); se += pv[nt]; }
#pragma unroll
      for (int m = 1; m < 16; m <<= 1) se += __shfl_xor(se, m, 64);
      float inv = 1.0f / se;
      int rown = mt * 16 + quad * 4 + rr;
#pragma unroll
      for (int nt = 0; nt < 4; nt++)
        P[wave][rown * 72 + nt * 16 + l15] = f2bf(pv[nt] * inv);
    }
  __syncthreads();
  short8 ap[4][2], bv[2][2];
#pragma unroll
  for (int mt = 0; mt < 4; mt++)
#pragma unroll
    for (int ks = 0; ks < 2; ks++)
      ap[mt][ks] = *(const short8*)&P[wave][(mt * 16 + l15) * 72 + ks * 32 + quad * 8];
#pragma unroll
  for (int nt = 0; nt < 2; nt++)
#pragma unroll
    for (int ks = 0; ks < 2; ks++)
      bv[nt][ks] = *(const short8*)&vh[(nt * 16 + l15) * 64 + ks * 32 + quad * 8];
  f32x4 O[4][2];
#pragma unroll
  for (int mt = 0; mt < 4; mt++)
#pragma unroll
    for (int nt = 0; nt < 2; nt++) {
      O[mt][nt] = z;
      O[mt][nt] = MFMA16(ap[mt][0], bv[nt][0], O[mt][nt]);
      O[mt][nt] = MFMA16(ap[mt][1], bv[nt][1], O[mt][nt]);
    }
#pragma unroll
  for (int mt = 0; mt < 4; mt++)
#pragma unroll
    for (int nt = 0; nt < 2; nt++)
#pragma unroll
      for (int r = 0; r < 4; r++) {
        int tok = mt * 16 + quad * 4 + r, d = nt * 16 + l15;
        ao[((size_t)win * 64 + tok) * 384 + h * 32 + d] = f2bf(O[mt][nt][r]);
      }
}

// ---------------- K4: proj GEMM + bias + LayerNorm2 fused (full row per WG) ----------------
__global__ __launch_bounds__(256) void k4_proj_ln2(const u16* __restrict__ ao, const u16* __restrict__ wt,
                                                   const float* __restrict__ pb,
                                                   const float* __restrict__ nw,
                                                   const float* __restrict__ nb,
                                                   u16* __restrict__ y1) {
  __shared__ alignas(16) u16 As[64 * 32];
  __shared__ alignas(16) u16 Bs[384 * 32];
  __shared__ float redS[4][64], redQ[4][64];
  int tid = threadIdx.x, lane = tid & 63, wave = tid >> 6;
  int l15 = lane & 15, quad = lane >> 4;
  size_t row0 = (size_t)blockIdx.x * 64;
  f32x4 z = {0.f, 0.f, 0.f, 0.f};
  f32x4 acc[4][6];
#pragma unroll
  for (int i = 0; i < 4; i++)
#pragma unroll
    for (int j = 0; j < 6; j++) acc[i][j] = z;
  int sr = tid >> 2, sc = (tid & 3) * 8;
  for (int k0 = 0; k0 < 384; k0 += 32) {
    __syncthreads();
    *(short8*)&As[sr * 32 + sc] = *(const short8*)&ao[(row0 + sr) * 384 + k0 + sc];
#pragma unroll
    for (int i = 0; i < 6; i++) {
      int e = tid * 8 + i * 2048;
      int r = e >> 5;
      *(short8*)&Bs[e] = *(const short8*)&wt[(size_t)r * 384 + k0 + (e & 31)];
    }
    __syncthreads();
    short8 af[4];
#pragma unroll
    for (int i = 0; i < 4; i++) af[i] = *(const short8*)&As[(i * 16 + l15) * 32 + quad * 8];
#pragma unroll
    for (int j = 0; j < 6; j++) {
      short8 bf = *(const short8*)&Bs[(wave * 96 + j * 16 + l15) * 32 + quad * 8];
#pragma unroll
      for (int i = 0; i < 4; i++) acc[i][j] = MFMA16(af[i], bf, acc[i][j]);
    }
  }
  float pb6[6], nw6[6], nb6[6];
#pragma unroll
  for (int j = 0; j < 6; j++) {
    int col = wave * 96 + j * 16 + l15;
    pb6[j] = pb[col]; nw6[j] = nw[col]; nb6[j] = nb[col];
  }
#pragma unroll
  for (int i = 0; i < 4; i++)
#pragma unroll
    for (int r = 0; r < 4; r++) {
      float s = 0.f, q = 0.f;
#pragma unroll
      for (int j = 0; j < 6; j++) {
        float v = acc[i][j][r] + pb6[j];
        s += v; q += v * v;
      }
#pragma unroll
      for (int m = 1; m < 16; m <<= 1) { s += __shfl_xor(s, m, 64); q += __shfl_xor(q, m, 64); }
      if (l15 == 0) {
        redS[wave][i * 16 + quad * 4 + r] = s;
        redQ[wave][i * 16 + quad * 4 + r] = q;
      }
    }
  __syncthreads();
#pragma unroll
  for (int i = 0; i < 4; i++)
#pragma unroll
    for (int r = 0; r < 4; r++) {
      int row = i * 16 + quad * 4 + r;
      float s = redS[0][row] + redS[1][row] + redS[2][row] + redS[3][row];
      float q = redQ[0][row] + redQ[1][row] + redQ[2][row] + redQ[3][row];
      float m = s * (1.0f / 384.0f);
      float rstd = rsqrtf(q * (1.0f / 384.0f) - m * m + 1e-5f);
#pragma unroll
      for (int j = 0; j < 6; j++) {
        int col = wave * 96 + j * 16 + l15;
        float v = acc[i][j][r] + pb6[j];
        y1[(row0 + row) * 384 + col] = f2bf((v - m) * rstd * nw6[j] + nb6[j]);
      }
    }
}

// ---------------- K5: fc1 GEMM + exact GELU ----------------
__global__ __launch_bounds__(256) void k5_fc1gelu(const u16* __restrict__ y1, const u16* __restrict__ wt,
                                                  const float* __restrict__ bias,
                                                  u16* __restrict__ hm) {
  __shared__ alignas(16) u16 As[128 * 32];
  __shared__ alignas(16) u16 Bs[128 * 32];
  int tid = threadIdx.x, lane = tid & 63, wave = tid >> 6;
  int l15 = lane & 15, quad = lane >> 4;
  int wr = wave >> 1, wc = wave & 1;
  int mblk = blockIdx.x % 1024, nblk = blockIdx.x / 1024;
  int row0 = mblk * 128, col0 = nblk * 128;
  f32x4 z = {0.f, 0.f, 0.f, 0.f};
  f32x4 acc[4][4];
#pragma unroll
  for (int i = 0; i < 4; i++)
#pragma unroll
    for (int j = 0; j < 4; j++) acc[i][j] = z;
  int sr = tid >> 2, sc = (tid & 3) * 8;
  for (int k0 = 0; k0 < 384; k0 += 32) {
    __syncthreads();
    *(short8*)&As[sr * 32 + sc] = *(const short8*)&y1[(size_t)(row0 + sr) * 384 + k0 + sc];
    *(short8*)&As[(sr + 64) * 32 + sc] = *(const short8*)&y1[(size_t)(row0 + sr + 64) * 384 + k0 + sc];
    *(short8*)&Bs[sr * 32 + sc] = *(const short8*)&wt[(size_t)(col0 + sr) * 384 + k0 + sc];
    *(short8*)&Bs[(sr + 64) * 32 + sc] = *(const short8*)&wt[(size_t)(col0 + sr + 64) * 384 + k0 + sc];
    __syncthreads();
    tile_step_128(As, Bs, wr, wc, l15, quad, acc);
  }
#pragma unroll
  for (int j = 0; j < 4; j++) {
    int ocol = col0 + wc * 64 + j * 16 + l15;
    float bo = bias[ocol];
#pragma unroll
    for (int i = 0; i < 4; i++)
#pragma unroll
      for (int r = 0; r < 4; r++) {
        int row = row0 + wr * 64 + i * 16 + quad * 4 + r;
        float val = acc[i][j][r] + bo;
        float g = 0.5f * val * (1.0f + erff(val * 0.70710678118654752f));
        hm[(size_t)row * 768 + ocol] = f2bf(g);
      }
  }
}

// ---------------- K6: fc2 GEMM + 2D window-merge + residual add ----------------
__global__ __launch_bounds__(256) void k6_fc2_merge(const u16* __restrict__ hm, const u16* __restrict__ wt,
                                                    const float* __restrict__ b2,
                                                    const float* __restrict__ x,
                                                    float* __restrict__ out) {
  __shared__ alignas(16) u16 As[128 * 32];
  __shared__ alignas(16) u16 Bs[128 * 32];
  __shared__ alignas(16) u16 TB[128][132];
  int tid = threadIdx.x, lane = tid & 63, wave = tid >> 6;
  int l15 = lane & 15, quad = lane >> 4;
  int wr = wave >> 1, wc = wave & 1;
  int bi = blockIdx.x;
  int ct = bi % 3; bi /= 3;
  int jh = bi % 8; bi /= 8;
  int ih = bi % 16; bi /= 16;
  int b = bi;
  int tbase = (b * 256 + ih * 16) * 64 + jh * 8;
  f32x4 z = {0.f, 0.f, 0.f, 0.f};
  f32x4 acc[4][4];
#pragma unroll
  for (int i = 0; i < 4; i++)
#pragma unroll
    for (int j = 0; j < 4; j++) acc[i][j] = z;
  int sr = tid >> 2, sc = (tid & 3) * 8;
  int sr2 = sr + 64;
  int t0 = tbase + (sr >> 3) * 64 + (sr & 7);
  int t1 = tbase + (sr2 >> 3) * 64 + (sr2 & 7);
  for (int k0 = 0; k0 < 768; k0 += 32) {
    __syncthreads();
    *(short8*)&As[sr * 32 + sc] = *(const short8*)&hm[(size_t)t0 * 768 + k0 + sc];
    *(short8*)&As[sr2 * 32 + sc] = *(const short8*)&hm[(size_t)t1 * 768 + k0 + sc];
    *(short8*)&Bs[sr * 32 + sc] = *(const short8*)&wt[(size_t)(ct * 128 + sr) * 768 + k0 + sc];
    *(short8*)&Bs[sr2 * 32 + sc] = *(const short8*)&wt[(size_t)(ct * 128 + sr2) * 768 + k0 + sc];
    __syncthreads();
    tile_step_128(As, Bs, wr, wc, l15, quad, acc);
  }
#pragma unroll
  for (int jj = 0; jj < 4; jj++) {
    int col = wc * 64 + jj * 16 + l15;
    float bb = b2[ct * 128 + col];
#pragma unroll
    for (int ii = 0; ii < 4; ii++)
#pragma unroll
      for (int r = 0; r < 4; r++) {
        int row = wr * 64 + ii * 16 + quad * 4 + r;
        TB[col][row] = f2bf(acc[ii][jj][r] + bb);
      }
  }
  __syncthreads();
  int hout = ih * 8 + jh;
  int wq = (lane & 31) * 4;
  int chalf = wave * 2 + (lane >> 5);
#pragma unroll
  for (int it = 0; it < 16; it++) {
    int cl = it * 8 + chalf;
    size_t gidx = (((size_t)b * 384 + ct * 128 + cl) * 128 + hout) * 128 + wq;
    float4 xv = *(const float4*)&x[gidx];
    ushort4 tv = *(const ushort4*)&TB[cl][wq];
    float4 ov;
    ov.x = bf2f(tv.x) + xv.x;
    ov.y = bf2f(tv.y) + xv.y;
    ov.z = bf2f(tv.z) + xv.z;
    ov.w = bf2f(tv.w) + xv.w;
    *(float4*)&out[gidx] = ov;
  }
}

extern "C" void kernel_launch(void* const* d_in, const int* in_sizes, int n_in,
                              void* d_out, int out_size, void* d_ws, size_t ws_size,
                              hipStream_t stream) {
  const float* x = (const float*)d_in[0];
  const float* n1w = (const float*)d_in[3];
  const float* n1b = (const float*)d_in[4];
  const float* qkvw = (const float*)d_in[5];
  const float* qkvb = (const float*)d_in[6];
  const float* projw = (const float*)d_in[7];
  const float* projb = (const float*)d_in[8];
  const float* relb = (const float*)d_in[9];
  const float* n2w = (const float*)d_in[10];
  const float* n2b = (const float*)d_in[11];
  const float* fc1w = (const float*)d_in[12];
  const float* fc1b = (const float*)d_in[13];
  const float* fc2w = (const float*)d_in[14];
  const float* fc2b = (const float*)d_in[15];

  char* w = (char*)d_ws;
  u16* wqkv = (u16*)w;  w += 884736;
  u16* wproj = (u16*)w; w += 294912;
  u16* wfc1 = (u16*)w;  w += 589824;
  u16* wfc2 = (u16*)w;  w += 589824;
  float* bias12 = (float*)w; w += 196608;
  u16* bufA = (u16*)w; w += 100663296;  // xn, later y1
  u16* bufB = (u16*)w; w += 100663296;  // vT, later hmid (spans B+C)
  u16* bufC = (u16*)w; w += 100663296;  // attnout

  u16* xn = bufA;
  u16* qb = (u16*)d_out;            // q and k parked in d_out (exactly fits)
  u16* kb = qb + 50331648;
  u16* vtb = bufB;
  u16* ao = bufC;
  u16* y1 = bufA;
  u16* hm = bufB;                    // 192 MB spans bufB+bufC
  float* out = (float*)d_out;

  k0_prep<<<dim3(4800), dim3(256), 0, stream>>>(qkvw, projw, fc1w, fc2w, relb,
                                                wqkv, wproj, wfc1, wfc2, bias12);
  k1_ln1<<<dim3(2048), dim3(256), 0, stream>>>(x, n1w, n1b, xn);
  k2_qkv<<<dim3(9216), dim3(256), 0, stream>>>(xn, wqkv, qkvb, qb, kb, vtb);
  k3_attn<<<dim3(6144), dim3(256), 0, stream>>>(qb, kb, vtb, bias12, ao);
  k4_proj_ln2<<<dim3(2048), dim3(256), 0, stream>>>(ao, wproj, projb, n2w, n2b, y1);
  k5_fc1gelu<<<dim3(6144), dim3(256), 0, stream>>>(y1, wfc1, fc1b, hm);
  k6_fc2_merge<<<dim3(3072), dim3(256), 0, stream>>>(hm, wfc2, fc2b, x, out);
}

// Round 2
// 1314.921 us; speedup vs baseline: 1.2192x; 1.2192x over previous
//
#include <hip/hip_runtime.h>
#include <math.h>

#define HWPIX 16384

typedef unsigned short u16;
typedef __attribute__((ext_vector_type(8))) short short8;
typedef __attribute__((ext_vector_type(4))) float f32x4;

__device__ __forceinline__ float bf2f(u16 h) { return __uint_as_float(((unsigned)h) << 16); }
__device__ __forceinline__ u16 f2bf(float f) {
  unsigned u = __float_as_uint(f);
  u += 0x7fffu + ((u >> 16) & 1u);
  return (u16)(u >> 16);
}

#define MFMA16(a, b, c) __builtin_amdgcn_mfma_f32_16x16x32_bf16((a), (b), (c), 0, 0, 0)

// async global->LDS, 16B per lane; LDS dest is wave-uniform base + lane*16
__device__ __forceinline__ void gl_lds16(const void* g, void* l) {
  __builtin_amdgcn_global_load_lds(
      (const __attribute__((address_space(1))) unsigned int*)g,
      (__attribute__((address_space(3))) unsigned int*)l, 16, 0, 0);
}

// ---------------- K0: weight prep (bf16 transpose) + rel-pos bias table ----------------
__global__ __launch_bounds__(256) void k0_prep(
    const float* __restrict__ qkv_w, const float* __restrict__ proj_w,
    const float* __restrict__ fc1_w, const float* __restrict__ fc2_w,
    const float* __restrict__ relb,
    u16* __restrict__ wqkv, u16* __restrict__ wproj,
    u16* __restrict__ wfc1, u16* __restrict__ wfc2, float* __restrict__ bias12) {
  int e = blockIdx.x * 256 + threadIdx.x;
  if (e < 442368) { int o = e / 384, i = e % 384; wqkv[e] = f2bf(qkv_w[i * 1152 + o]); return; }
  e -= 442368;
  if (e < 147456) { int o = e / 384, i = e % 384; wproj[e] = f2bf(proj_w[i * 384 + o]); return; }
  e -= 147456;
  if (e < 294912) { int o = e / 384, i = e % 384; wfc1[e] = f2bf(fc1_w[i * 768 + o]); return; }
  e -= 294912;
  if (e < 294912) { int o = e / 768, i = e % 768; wfc2[e] = f2bf(fc2_w[i * 384 + o]); return; }
  e -= 294912;
  if (e < 49152) {
    int h = e / 4096, r = e % 4096, n = r / 64, m = r % 64;
    int dy = n / 8 - m / 8 + 7, dx = n % 8 - m % 8 + 7;
    bias12[e] = relb[(dy * 15 + dx) * 12 + h];
  }
}

// ---------------- K1: LayerNorm1 + NCHW->(token,C) transpose, bf16 out ----------------
__global__ __launch_bounds__(256) void k1_ln1(const float* __restrict__ x,
                                              const float* __restrict__ nw,
                                              const float* __restrict__ nb,
                                              u16* __restrict__ xn) {
  __shared__ alignas(16) u16 raw[64][392];
  __shared__ float psum[4][64], psq[4][64];
  int win = blockIdx.x;
  int b = win >> 8, s = win & 255;
  int wave = threadIdx.x >> 6, lane = threadIdx.x & 63;
  const float* xb = x + (size_t)b * 384 * HWPIX + s * 64 + lane;
  float sum = 0.f, sq = 0.f;
  for (int c = wave; c < 384; c += 4) {
    float v = xb[(size_t)c * HWPIX];
    sum += v; sq += v * v;
    raw[lane][c] = f2bf(v);
  }
  psum[wave][lane] = sum; psq[wave][lane] = sq;
  __syncthreads();
#pragma unroll
  for (int tt = 0; tt < 2; tt++) {
    int t = tt * 32 + wave * 8 + (lane >> 3);
    float s4 = psum[0][t] + psum[1][t] + psum[2][t] + psum[3][t];
    float q4 = psq[0][t] + psq[1][t] + psq[2][t] + psq[3][t];
    float m = s4 * (1.0f / 384.0f);
    float rstd = rsqrtf(q4 * (1.0f / 384.0f) - m * m + 1e-5f);
    u16* orow = xn + ((size_t)win * 64 + t) * 384;
#pragma unroll
    for (int it = 0; it < 12; it++) {
      int c = (lane & 7) * 4 + it * 32;
      ushort4 rv = *(const ushort4*)&raw[t][c];
      float4 nwv = *(const float4*)&nw[c];
      float4 nbv = *(const float4*)&nb[c];
      ushort4 ov;
      ov.x = f2bf((bf2f(rv.x) - m) * rstd * nwv.x + nbv.x);
      ov.y = f2bf((bf2f(rv.y) - m) * rstd * nwv.y + nbv.y);
      ov.z = f2bf((bf2f(rv.z) - m) * rstd * nwv.z + nbv.z);
      ov.w = f2bf((bf2f(rv.w) - m) * rstd * nwv.w + nbv.w);
      *(ushort4*)&orow[c] = ov;
    }
  }
}

// ---------------- shared 128x128 tile MFMA step ----------------
__device__ __forceinline__ void tile_step_128(const u16* As, const u16* Bs, int wr, int wc,
                                              int l15, int quad, f32x4 acc[4][4]) {
  short8 af[4], bf[4];
#pragma unroll
  for (int i = 0; i < 4; i++)
    af[i] = *(const short8*)&As[(wr * 64 + i * 16 + l15) * 32 + quad * 8];
#pragma unroll
  for (int j = 0; j < 4; j++)
    bf[j] = *(const short8*)&Bs[(wc * 64 + j * 16 + l15) * 32 + quad * 8];
#pragma unroll
  for (int i = 0; i < 4; i++)
#pragma unroll
    for (int j = 0; j < 4; j++)
      acc[i][j] = MFMA16(af[i], bf[j], acc[i][j]);
}

// ---------------- K2: QKV GEMM (async LDS staging) + LDS-transposed scatter ----------------
__global__ __launch_bounds__(256) void k2_qkv(const u16* __restrict__ xn, const u16* __restrict__ wt,
                                              const float* __restrict__ bias,
                                              u16* __restrict__ qb, u16* __restrict__ kb,
                                              u16* __restrict__ vtb) {
  __shared__ alignas(16) u16 smem[17408];  // As(4096) + Bs(4096) aliased with tile(128*136)
  u16* As = smem;
  u16* Bs = smem + 4096;
  u16* tile = smem;
  int tid = threadIdx.x, lane = tid & 63, wave = tid >> 6;
  int l15 = lane & 15, quad = lane >> 4;
  int wr = wave >> 1, wc = wave & 1;
  int nblk = blockIdx.x % 9, mblk = blockIdx.x / 9;  // N-inner: A-tile reuse in cache
  int row0 = mblk * 128, col0 = nblk * 128;
  int part = nblk / 3, subcol0 = (nblk % 3) * 128;
  f32x4 z = {0.f, 0.f, 0.f, 0.f};
  f32x4 acc[4][4];
#pragma unroll
  for (int i = 0; i < 4; i++)
#pragma unroll
    for (int j = 0; j < 4; j++) acc[i][j] = z;
  int lrow = lane >> 2, lcol = (lane & 3) * 8;
  const u16* ga0 = &xn[(size_t)(row0 + wave * 32 + lrow) * 384 + lcol];
  const u16* ga1 = ga0 + 16 * 384;
  const u16* gb0 = &wt[(size_t)(col0 + wave * 32 + lrow) * 384 + lcol];
  const u16* gb1 = gb0 + 16 * 384;
  u16* lA0 = &As[(wave * 32) * 32];
  u16* lA1 = &As[(wave * 32 + 16) * 32];
  u16* lB0 = &Bs[(wave * 32) * 32];
  u16* lB1 = &Bs[(wave * 32 + 16) * 32];
  for (int k0 = 0; k0 < 384; k0 += 32) {
    __syncthreads();
    gl_lds16(ga0 + k0, lA0);
    gl_lds16(ga1 + k0, lA1);
    gl_lds16(gb0 + k0, lB0);
    gl_lds16(gb1 + k0, lB1);
    __syncthreads();
    tile_step_128(As, Bs, wr, wc, l15, quad, acc);
  }
  __syncthreads();  // all waves done reading As/Bs before tile overwrite
  if (part < 2) {
    float s = (part == 0) ? 0.17677669529663687f : 1.0f;
#pragma unroll
    for (int j = 0; j < 4; j++) {
      int col = wc * 64 + j * 16 + l15;
      float bo = bias[part * 384 + subcol0 + col];
#pragma unroll
      for (int i = 0; i < 4; i++)
#pragma unroll
        for (int r = 0; r < 4; r++) {
          int row = wr * 64 + i * 16 + quad * 4 + r;
          tile[row * 136 + col] = f2bf((acc[i][j][r] + bo) * s);
        }
    }
  } else {
#pragma unroll
    for (int j = 0; j < 4; j++) {
      int col = wc * 64 + j * 16 + l15;
      float bo = bias[768 + subcol0 + col];
#pragma unroll
      for (int i = 0; i < 4; i++) {
        int rowst = wr * 64 + i * 16 + quad * 4;
        ushort4 pk;
        pk.x = f2bf(acc[i][j][0] + bo);
        pk.y = f2bf(acc[i][j][1] + bo);
        pk.z = f2bf(acc[i][j][2] + bo);
        pk.w = f2bf(acc[i][j][3] + bo);
        *(ushort4*)&tile[col * 136 + rowst] = pk;  // transposed: tile[d][tok]
      }
    }
  }
  __syncthreads();
  int hb = subcol0 >> 5;  // first head in this block (4 heads)
  int win0 = row0 >> 6;
  u16* dst0 = (part == 0) ? qb : (part == 1) ? kb : vtb;
#pragma unroll
  for (int c = 0; c < 8; c++) {
    int wl = c >> 2, hl = c & 3;
    int wh = (win0 + wl) * 12 + hb + hl;
    u16* dst = dst0 + (size_t)wh * 2048 + tid * 8;
    short8 v;
    if (part < 2)
      v = *(const short8*)&tile[(wl * 64 + (tid >> 2)) * 136 + hl * 32 + (tid & 3) * 8];
    else
      v = *(const short8*)&tile[(hl * 32 + (tid >> 3)) * 136 + wl * 64 + (tid & 7) * 8];
    *(short8*)dst = v;
  }
}

// ---------------- K3: windowed attention (one wave per (window,head)) ----------------
__global__ __launch_bounds__(256) void k3_attn(const u16* __restrict__ qb, const u16* __restrict__ kb,
                                               const u16* __restrict__ vtb,
                                               const float* __restrict__ bias12,
                                               u16* __restrict__ ao) {
  __shared__ alignas(16) u16 P[4][64 * 72];
  int tid = threadIdx.x, lane = tid & 63, wave = tid >> 6;
  int l15 = lane & 15, quad = lane >> 4;
  int wh = blockIdx.x * 4 + wave;
  int win = wh / 12, h = wh % 12;
  const u16* qh = qb + (size_t)wh * 2048;
  const u16* kh = kb + (size_t)wh * 2048;
  const u16* vh = vtb + (size_t)wh * 2048;
  short8 aq[4], bk[4];
#pragma unroll
  for (int t = 0; t < 4; t++) {
    aq[t] = *(const short8*)&qh[(t * 16 + l15) * 32 + quad * 8];
    bk[t] = *(const short8*)&kh[(t * 16 + l15) * 32 + quad * 8];
  }
  f32x4 z = {0.f, 0.f, 0.f, 0.f};
  f32x4 S[4][4];
#pragma unroll
  for (int mt = 0; mt < 4; mt++)
#pragma unroll
    for (int nt = 0; nt < 4; nt++) S[mt][nt] = MFMA16(aq[mt], bk[nt], z);
  const float* bh = bias12 + h * 4096;
#pragma unroll
  for (int mt = 0; mt < 4; mt++)
#pragma unroll
    for (int rr = 0; rr < 4; rr++) {
      int rown = mt * 16 + quad * 4 + rr;
#pragma unroll
      for (int nt = 0; nt < 4; nt++) S[mt][nt][rr] += bh[rown * 64 + nt * 16 + l15];
    }
#pragma unroll
  for (int mt = 0; mt < 4; mt++)
#pragma unroll
    for (int rr = 0; rr < 4; rr++) {
      float mx = S[mt][0][rr];
      mx = fmaxf(mx, S[mt][1][rr]);
      mx = fmaxf(mx, S[mt][2][rr]);
      mx = fmaxf(mx, S[mt][3][rr]);
#pragma unroll
      for (int m = 1; m < 16; m <<= 1) mx = fmaxf(mx, __shfl_xor(mx, m, 64));
      float pv[4], se = 0.f;
#pragma unroll
      for (int nt = 0; nt < 4; nt++) { pv[nt] = __expf(S[mt][nt][rr] - mx); se += pv[nt]; }
#pragma unroll
      for (int m = 1; m < 16; m <<= 1) se += __shfl_xor(se, m, 64);
      float inv = 1.0f / se;
      int rown = mt * 16 + quad * 4 + rr;
#pragma unroll
      for (int nt = 0; nt < 4; nt++)
        P[wave][rown * 72 + nt * 16 + l15] = f2bf(pv[nt] * inv);
    }
  __syncthreads();
  short8 ap[4][2], bv[2][2];
#pragma unroll
  for (int mt = 0; mt < 4; mt++)
#pragma unroll
    for (int ks = 0; ks < 2; ks++)
      ap[mt][ks] = *(const short8*)&P[wave][(mt * 16 + l15) * 72 + ks * 32 + quad * 8];
#pragma unroll
  for (int nt = 0; nt < 2; nt++)
#pragma unroll
    for (int ks = 0; ks < 2; ks++)
      bv[nt][ks] = *(const short8*)&vh[(nt * 16 + l15) * 64 + ks * 32 + quad * 8];
  f32x4 O[4][2];
#pragma unroll
  for (int mt = 0; mt < 4; mt++)
#pragma unroll
    for (int nt = 0; nt < 2; nt++) {
      O[mt][nt] = z;
      O[mt][nt] = MFMA16(ap[mt][0], bv[nt][0], O[mt][nt]);
      O[mt][nt] = MFMA16(ap[mt][1], bv[nt][1], O[mt][nt]);
    }
#pragma unroll
  for (int mt = 0; mt < 4; mt++)
#pragma unroll
    for (int nt = 0; nt < 2; nt++)
#pragma unroll
      for (int r = 0; r < 4; r++) {
        int tok = mt * 16 + quad * 4 + r, d = nt * 16 + l15;
        ao[((size_t)win * 64 + tok) * 384 + h * 32 + d] = f2bf(O[mt][nt][r]);
      }
}

// ---------------- K4: proj GEMM + bias + LayerNorm2 fused (full row per WG) ----------------
__global__ __launch_bounds__(256) void k4_proj_ln2(const u16* __restrict__ ao, const u16* __restrict__ wt,
                                                   const float* __restrict__ pb,
                                                   const float* __restrict__ nw,
                                                   const float* __restrict__ nb,
                                                   u16* __restrict__ y1) {
  __shared__ alignas(16) u16 As[64 * 32];
  __shared__ alignas(16) u16 Bs[384 * 32];
  __shared__ float redS[4][64], redQ[4][64];
  int tid = threadIdx.x, lane = tid & 63, wave = tid >> 6;
  int l15 = lane & 15, quad = lane >> 4;
  size_t row0 = (size_t)blockIdx.x * 64;
  f32x4 z = {0.f, 0.f, 0.f, 0.f};
  f32x4 acc[4][6];
#pragma unroll
  for (int i = 0; i < 4; i++)
#pragma unroll
    for (int j = 0; j < 6; j++) acc[i][j] = z;
  int lrow = lane >> 2, lcol = (lane & 3) * 8;
  const u16* ga = &ao[(row0 + wave * 16 + lrow) * 384 + lcol];
  u16* lA = &As[(wave * 16) * 32];
  const u16* gB[6];
  u16* lB[6];
#pragma unroll
  for (int t = 0; t < 6; t++) {
    gB[t] = &wt[(size_t)(wave * 96 + t * 16 + lrow) * 384 + lcol];
    lB[t] = &Bs[(wave * 96 + t * 16) * 32];
  }
  for (int k0 = 0; k0 < 384; k0 += 32) {
    __syncthreads();
    gl_lds16(ga + k0, lA);
#pragma unroll
    for (int t = 0; t < 6; t++) gl_lds16(gB[t] + k0, lB[t]);
    __syncthreads();
    short8 af[4];
#pragma unroll
    for (int i = 0; i < 4; i++) af[i] = *(const short8*)&As[(i * 16 + l15) * 32 + quad * 8];
#pragma unroll
    for (int j = 0; j < 6; j++) {
      short8 bf = *(const short8*)&Bs[(wave * 96 + j * 16 + l15) * 32 + quad * 8];
#pragma unroll
      for (int i = 0; i < 4; i++) acc[i][j] = MFMA16(af[i], bf, acc[i][j]);
    }
  }
  float pb6[6], nw6[6], nb6[6];
#pragma unroll
  for (int j = 0; j < 6; j++) {
    int col = wave * 96 + j * 16 + l15;
    pb6[j] = pb[col]; nw6[j] = nw[col]; nb6[j] = nb[col];
  }
#pragma unroll
  for (int i = 0; i < 4; i++)
#pragma unroll
    for (int r = 0; r < 4; r++) {
      float s = 0.f, q = 0.f;
#pragma unroll
      for (int j = 0; j < 6; j++) {
        float v = acc[i][j][r] + pb6[j];
        s += v; q += v * v;
      }
#pragma unroll
      for (int m = 1; m < 16; m <<= 1) { s += __shfl_xor(s, m, 64); q += __shfl_xor(q, m, 64); }
      if (l15 == 0) {
        redS[wave][i * 16 + quad * 4 + r] = s;
        redQ[wave][i * 16 + quad * 4 + r] = q;
      }
    }
  __syncthreads();
#pragma unroll
  for (int i = 0; i < 4; i++)
#pragma unroll
    for (int r = 0; r < 4; r++) {
      int row = i * 16 + quad * 4 + r;
      float s = redS[0][row] + redS[1][row] + redS[2][row] + redS[3][row];
      float q = redQ[0][row] + redQ[1][row] + redQ[2][row] + redQ[3][row];
      float m = s * (1.0f / 384.0f);
      float rstd = rsqrtf(q * (1.0f / 384.0f) - m * m + 1e-5f);
#pragma unroll
      for (int j = 0; j < 6; j++) {
        int col = wave * 96 + j * 16 + l15;
        float v = acc[i][j][r] + pb6[j];
        y1[(row0 + row) * 384 + col] = f2bf((v - m) * rstd * nw6[j] + nb6[j]);
      }
    }
}

// ---------------- K5: fc1 GEMM + exact GELU, LDS-transposed coalesced store ----------------
__global__ __launch_bounds__(256) void k5_fc1gelu(const u16* __restrict__ y1, const u16* __restrict__ wt,
                                                  const float* __restrict__ bias,
                                                  u16* __restrict__ hm) {
  __shared__ alignas(16) u16 smem[17408];
  u16* As = smem;
  u16* Bs = smem + 4096;
  u16* tile = smem;
  int tid = threadIdx.x, lane = tid & 63, wave = tid >> 6;
  int l15 = lane & 15, quad = lane >> 4;
  int wr = wave >> 1, wc = wave & 1;
  int nblk = blockIdx.x % 6, mblk = blockIdx.x / 6;
  int row0 = mblk * 128, col0 = nblk * 128;
  f32x4 z = {0.f, 0.f, 0.f, 0.f};
  f32x4 acc[4][4];
#pragma unroll
  for (int i = 0; i < 4; i++)
#pragma unroll
    for (int j = 0; j < 4; j++) acc[i][j] = z;
  int lrow = lane >> 2, lcol = (lane & 3) * 8;
  const u16* ga0 = &y1[(size_t)(row0 + wave * 32 + lrow) * 384 + lcol];
  const u16* ga1 = ga0 + 16 * 384;
  const u16* gb0 = &wt[(size_t)(col0 + wave * 32 + lrow) * 384 + lcol];
  const u16* gb1 = gb0 + 16 * 384;
  u16* lA0 = &As[(wave * 32) * 32];
  u16* lA1 = &As[(wave * 32 + 16) * 32];
  u16* lB0 = &Bs[(wave * 32) * 32];
  u16* lB1 = &Bs[(wave * 32 + 16) * 32];
  for (int k0 = 0; k0 < 384; k0 += 32) {
    __syncthreads();
    gl_lds16(ga0 + k0, lA0);
    gl_lds16(ga1 + k0, lA1);
    gl_lds16(gb0 + k0, lB0);
    gl_lds16(gb1 + k0, lB1);
    __syncthreads();
    tile_step_128(As, Bs, wr, wc, l15, quad, acc);
  }
  __syncthreads();
#pragma unroll
  for (int j = 0; j < 4; j++) {
    int col = wc * 64 + j * 16 + l15;
    float bo = bias[col0 + col];
#pragma unroll
    for (int i = 0; i < 4; i++)
#pragma unroll
      for (int r = 0; r < 4; r++) {
        int row = wr * 64 + i * 16 + quad * 4 + r;
        float val = acc[i][j][r] + bo;
        float g = 0.5f * val * (1.0f + erff(val * 0.70710678118654752f));
        tile[row * 136 + col] = f2bf(g);
      }
  }
  __syncthreads();
#pragma unroll
  for (int it = 0; it < 8; it++) {
    int row = it * 16 + (tid >> 4), colp = (tid & 15) * 8;
    short8 v = *(const short8*)&tile[row * 136 + colp];
    *(short8*)&hm[(size_t)(row0 + row) * 768 + col0 + colp] = v;
  }
}

// ---------------- K6: fc2 GEMM + 2D window-merge + residual add ----------------
__global__ __launch_bounds__(256) void k6_fc2_merge(const u16* __restrict__ hm, const u16* __restrict__ wt,
                                                    const float* __restrict__ b2,
                                                    const float* __restrict__ x,
                                                    float* __restrict__ out) {
  __shared__ alignas(16) u16 smem[16896];  // As(4096)+Bs(4096) aliased with TB(128*132)
  u16* As = smem;
  u16* Bs = smem + 4096;
  u16* TB = smem;
  int tid = threadIdx.x, lane = tid & 63, wave = tid >> 6;
  int l15 = lane & 15, quad = lane >> 4;
  int wr = wave >> 1, wc = wave & 1;
  int bi = blockIdx.x;
  int ct = bi % 3; bi /= 3;
  int jh = bi % 8; bi /= 8;
  int ih = bi % 16; bi /= 16;
  int b = bi;
  int tbase = (b * 256 + ih * 16) * 64 + jh * 8;
  f32x4 z = {0.f, 0.f, 0.f, 0.f};
  f32x4 acc[4][4];
#pragma unroll
  for (int i = 0; i < 4; i++)
#pragma unroll
    for (int j = 0; j < 4; j++) acc[i][j] = z;
  int lrow = lane >> 2, lcol = (lane & 3) * 8;
  int tr0 = wave * 32 + lrow, tr1 = tr0 + 16;
  int tok0 = tbase + (tr0 >> 3) * 64 + (tr0 & 7);
  int tok1 = tbase + (tr1 >> 3) * 64 + (tr1 & 7);
  const u16* ga0 = &hm[(size_t)tok0 * 768 + lcol];
  const u16* ga1 = &hm[(size_t)tok1 * 768 + lcol];
  const u16* gb0 = &wt[(size_t)(ct * 128 + tr0) * 768 + lcol];
  const u16* gb1 = &wt[(size_t)(ct * 128 + tr1) * 768 + lcol];
  u16* lA0 = &As[(wave * 32) * 32];
  u16* lA1 = &As[(wave * 32 + 16) * 32];
  u16* lB0 = &Bs[(wave * 32) * 32];
  u16* lB1 = &Bs[(wave * 32 + 16) * 32];
  for (int k0 = 0; k0 < 768; k0 += 32) {
    __syncthreads();
    gl_lds16(ga0 + k0, lA0);
    gl_lds16(ga1 + k0, lA1);
    gl_lds16(gb0 + k0, lB0);
    gl_lds16(gb1 + k0, lB1);
    __syncthreads();
    tile_step_128(As, Bs, wr, wc, l15, quad, acc);
  }
  __syncthreads();  // done reading As/Bs; TB aliases them
#pragma unroll
  for (int jj = 0; jj < 4; jj++) {
    int col = wc * 64 + jj * 16 + l15;
    float bb = b2[ct * 128 + col];
#pragma unroll
    for (int ii = 0; ii < 4; ii++)
#pragma unroll
      for (int r = 0; r < 4; r++) {
        int row = wr * 64 + ii * 16 + quad * 4 + r;
        TB[col * 132 + row] = f2bf(acc[ii][jj][r] + bb);
      }
  }
  __syncthreads();
  int hout = ih * 8 + jh;
  int wq = (lane & 31) * 4;
  int chalf = wave * 2 + (lane >> 5);
#pragma unroll
  for (int it = 0; it < 16; it++) {
    int cl = it * 8 + chalf;
    size_t gidx = (((size_t)b * 384 + ct * 128 + cl) * 128 + hout) * 128 + wq;
    float4 xv = *(const float4*)&x[gidx];
    ushort4 tv = *(const ushort4*)&TB[cl * 132 + wq];
    float4 ov;
    ov.x = bf2f(tv.x) + xv.x;
    ov.y = bf2f(tv.y) + xv.y;
    ov.z = bf2f(tv.z) + xv.z;
    ov.w = bf2f(tv.w) + xv.w;
    *(float4*)&out[gidx] = ov;
  }
}

extern "C" void kernel_launch(void* const* d_in, const int* in_sizes, int n_in,
                              void* d_out, int out_size, void* d_ws, size_t ws_size,
                              hipStream_t stream) {
  const float* x = (const float*)d_in[0];
  const float* n1w = (const float*)d_in[3];
  const float* n1b = (const float*)d_in[4];
  const float* qkvw = (const float*)d_in[5];
  const float* qkvb = (const float*)d_in[6];
  const float* projw = (const float*)d_in[7];
  const float* projb = (const float*)d_in[8];
  const float* relb = (const float*)d_in[9];
  const float* n2w = (const float*)d_in[10];
  const float* n2b = (const float*)d_in[11];
  const float* fc1w = (const float*)d_in[12];
  const float* fc1b = (const float*)d_in[13];
  const float* fc2w = (const float*)d_in[14];
  const float* fc2b = (const float*)d_in[15];

  char* w = (char*)d_ws;
  u16* wqkv = (u16*)w;  w += 884736;
  u16* wproj = (u16*)w; w += 294912;
  u16* wfc1 = (u16*)w;  w += 589824;
  u16* wfc2 = (u16*)w;  w += 589824;
  float* bias12 = (float*)w; w += 196608;
  u16* bufA = (u16*)w; w += 100663296;  // xn, later y1
  u16* bufB = (u16*)w; w += 100663296;  // vT, later hmid (spans B+C)
  u16* bufC = (u16*)w; w += 100663296;  // attnout

  u16* xn = bufA;
  u16* qb = (u16*)d_out;            // q and k parked in d_out (exactly fits)
  u16* kb = qb + 50331648;
  u16* vtb = bufB;
  u16* ao = bufC;
  u16* y1 = bufA;
  u16* hm = bufB;                    // 192 MB spans bufB+bufC
  float* out = (float*)d_out;

  k0_prep<<<dim3(4800), dim3(256), 0, stream>>>(qkvw, projw, fc1w, fc2w, relb,
                                                wqkv, wproj, wfc1, wfc2, bias12);
  k1_ln1<<<dim3(2048), dim3(256), 0, stream>>>(x, n1w, n1b, xn);
  k2_qkv<<<dim3(9216), dim3(256), 0, stream>>>(xn, wqkv, qkvb, qb, kb, vtb);
  k3_attn<<<dim3(6144), dim3(256), 0, stream>>>(qb, kb, vtb, bias12, ao);
  k4_proj_ln2<<<dim3(2048), dim3(256), 0, stream>>>(ao, wproj, projb, n2w, n2b, y1);
  k5_fc1gelu<<<dim3(6144), dim3(256), 0, stream>>>(y1, wfc1, fc1b, hm);
  k6_fc2_merge<<<dim3(3072), dim3(256), 0, stream>>>(hm, wfc2, fc2b, x, out);
}